// Round 11
// baseline (179.777 us; speedup 1.0000x reference)
//
#include <hip/hip_runtime.h>
#include <hip/hip_bf16.h>
#include <math.h>

#define DMODEL 1024
#define NHEAD  16
#define DHEAD  64
#define BATCH  2
#define SEQ    2048
#define MROWS  (BATCH * SEQ)   // 4096

typedef __attribute__((ext_vector_type(8))) __bf16 bf16x8;
typedef __attribute__((ext_vector_type(4))) float  f32x4;

// async global->LDS, 16 B per lane. LDS dest must be wave-uniform base + lane*16.
__device__ __forceinline__ void load16_lds(const ushort* g, ushort* l) {
    __builtin_amdgcn_global_load_lds(
        (const __attribute__((address_space(1))) unsigned int*)g,
        (__attribute__((address_space(3))) unsigned int*)l, 16, 0, 0);
}

__device__ __forceinline__ ushort bf16u(float v) {
    __hip_bfloat16 h = __float2bfloat16(v);
    return *reinterpret_cast<ushort*>(&h);
}

// ---------------------------------------------------------------------------
// fused fp32 -> bf16 cast of x (4M elems) + Wq/Wk/Wv/Wo (1M each, contiguous
// destination Wqkv..Wob). One dispatch, source picked by linear range.
// Kept SEPARATE from rope_tab: merging forces the memory-bound cast path to
// carry sincosf's register footprint (r9 vs r6: +3.4 us).
// ---------------------------------------------------------------------------
__global__ __launch_bounds__(256)
void cast_all(const float* __restrict__ x,  const float* __restrict__ w0,
              const float* __restrict__ w1, const float* __restrict__ w2,
              const float* __restrict__ w3, ushort* __restrict__ xb,
              ushort* __restrict__ wb) {
    const int idx = (blockIdx.x * 256 + threadIdx.x) * 8;   // 0..8M-8
    const int TEN_ = MROWS * DMODEL;                        // 4M
    const float* src;
    ushort* dst;
    if (idx < TEN_) {
        src = x + idx;  dst = xb + idx;
    } else {
        const int r   = idx - TEN_;                         // 0..4M-8
        const int sel = r >> 20;                            // 0..3 (WEL = 1M)
        const int off = r & (DMODEL * DMODEL - 1);
        src = (sel == 0 ? w0 : sel == 1 ? w1 : sel == 2 ? w2 : w3) + off;
        dst = wb + r;
    }
    const f32x4 a = *reinterpret_cast<const f32x4*>(src);
    const f32x4 b = *reinterpret_cast<const f32x4*>(src + 4);
    bf16x8 o;
    #pragma unroll
    for (int j = 0; j < 4; j++) { o[j] = (__bf16)a[j]; o[4 + j] = (__bf16)b[j]; }
    *reinterpret_cast<bf16x8*>(dst) = o;
}

// ---------------------------------------------------------------------------
// RoPE cos/sin table: tab[s*32+i] = (cos, sin) of pos[s] * 10000^(-2i/64).
// ---------------------------------------------------------------------------
__global__ __launch_bounds__(256)
void rope_tab(const int* __restrict__ pos, float2* __restrict__ tab) {
    const int idx = blockIdx.x * 256 + threadIdx.x;   // 0..65535
    const int s = idx >> 5;
    const int i = idx & 31;
    const float p = (float)pos[s];
    const float inv = exp2f(-(float)i * 0.41524101186092f);  // 2*log2(1e4)/64
    float sn, cs;
    sincosf(p * inv, &sn, &cs);
    tab[idx] = make_float2(cs, sn);
}

// ---------------------------------------------------------------------------
// Fused QKV GEMM, 256x256 tile, BK=64, 8 waves.
// Register-software-pipelined phases (round 3, unchanged — best measured).
// ---------------------------------------------------------------------------
#define QKV_BARRIER() do { asm volatile("" ::: "memory"); \
                           __builtin_amdgcn_s_barrier(); } while (0)

#define RD4(dst, p_)                                                          \
    _Pragma("unroll")                                                         \
    for (int rr_ = 0; rr_ < 4; rr_++)                                         \
        dst[rr_] = *reinterpret_cast<const bf16x8*>((p_) + rr_ * 512);

#define MFMA_G(AFR, BFR, IOFF)                                                \
    __builtin_amdgcn_s_setprio(1);                                            \
    _Pragma("unroll")                                                         \
    for (int im_ = 0; im_ < 4; im_++)                                         \
        _Pragma("unroll")                                                     \
        for (int jn_ = 0; jn_ < 4; jn_++)                                     \
            acc[(IOFF) + im_][jn_] = __builtin_amdgcn_mfma_f32_16x16x32_bf16( \
                AFR[im_], BFR[jn_], acc[(IOFF) + im_][jn_], 0, 0, 0);         \
    __builtin_amdgcn_s_setprio(0);

__global__ __launch_bounds__(512, 2)
void gemm_qkv(const ushort* __restrict__ A, const ushort* __restrict__ B,
              ushort* __restrict__ C, const float2* __restrict__ tab) {
    __shared__ __align__(16) ushort pool[65536];   // 128 KiB

    // bijective XCD remap: each XCD gets 2 full A-stripes (by pairs) x 12 bx
    const int orig = blockIdx.y * gridDim.x + blockIdx.x;   // 0..191
    const int xcd  = orig & 7;
    const int ixd  = orig >> 3;                             // 0..23
    const int by   = xcd * 2 + (ixd / 12);
    const int bx   = ixd % 12;
    const int m0   = by * 256;
    const int n0   = bx * 256;

    const int tid  = threadIdx.x;
    const int lane = tid & 63;
    const int w    = tid >> 6;
    const int l16  = lane & 15;
    const int quad = lane >> 4;
    const int wm   = (w >> 2) * 128;    // 2 wave-rows
    const int wn   = (w & 3) * 64;      // 4 wave-cols
    // read-side swizzled chunk offset (row&7 == l16&7 for all frag reads)
    const int chq  = (quad ^ ((l16 & 3) ^ ((l16 & 4) >> 1))) << 3;
    // staging coords: thread covers one 16B chunk per issue
    const int srow = tid >> 2;          // 0..127
    const int ssc  = (tid & 3) ^ ((srow & 3) ^ ((srow & 4) >> 1));

    // hoisted staging bases (pre-swizzled global source)
    const ushort* gA = A + (size_t)(m0 + srow) * DMODEL + ssc * 8;
    const ushort* gB = B + (size_t)(n0 + srow) * DMODEL + ssc * 8;

    auto stageA = [&](int tt, int ks) {
        const int off = tt * 64 + ks * 32;
        const int lb  = ((tt & 1) << 15) + (ks << 13);
        load16_lds(gA + off,                &pool[lb + tid * 8]);
        load16_lds(gA + 128 * DMODEL + off, &pool[lb + 4096 + tid * 8]);
    };
    auto stageB = [&](int tt, int ks) {
        const int off = tt * 64 + ks * 32;
        const int lb  = ((tt & 1) << 15) + 16384 + (ks << 13);
        load16_lds(gB + off,                &pool[lb + tid * 8]);
        load16_lds(gB + 128 * DMODEL + off, &pool[lb + 4096 + tid * 8]);
    };

    // prologue: AB(0,0), AB(0,1), AB(1,0)  [12 loads]
    stageA(0, 0); stageB(0, 0);
    stageA(0, 1); stageB(0, 1);
    stageA(1, 0); stageB(1, 0);

    f32x4 acc[8][4];
    #pragma unroll
    for (int i = 0; i < 8; i++)
        #pragma unroll
        for (int j = 0; j < 4; j++) acc[i][j] = (f32x4){0.f, 0.f, 0.f, 0.f};

    asm volatile("s_waitcnt vmcnt(4)" ::: "memory");  // AB(0,0..1) landed
    __builtin_amdgcn_s_barrier();

    bf16x8 al[4], ah[4], bc[4], bn[4];

    // pre-loop: operands of phase (0, ks0)
    { const ushort* p = pool + (wm + l16) * 32 + chq;           RD4(al, p); }
    { const ushort* q = pool + 16384 + (wn + l16) * 32 + chq;   RD4(bc, q); }

    #pragma unroll 1
    for (int t = 0; t < 16; t++) {
        const int buf  = (t & 1) << 15;
        const int bufn = buf ^ 32768;
        // ---------- P0: MFMA (t,ks0); prefetch (t,ks1)
        if (t <= 14) { stageA(t + 1, 1); stageB(t + 1, 1); }
        { const ushort* p = pool + buf + (wm + 64 + l16) * 32 + chq;
          RD4(ah, p); }                               // A-hi (t,ks0)
        MFMA_G(al, bc, 0);                            // acc[0..3]
        { const ushort* p = pool + buf + 8192 + (wm + l16) * 32 + chq;
          RD4(al, p);                                 // A-lo (t,ks1)
          const ushort* q = pool + buf + 16384 + 8192 + (wn + l16) * 32 + chq;
          RD4(bn, q); }                               // B    (t,ks1)
        MFMA_G(ah, bc, 4);                            // acc[4..7]
        if (t <= 14) { asm volatile("s_waitcnt vmcnt(4)" ::: "memory"); }
        QKV_BARRIER();
        // ---------- P1: MFMA (t,ks1); prefetch (t+1,ks0)
        if (t <= 13) { stageA(t + 2, 0); stageB(t + 2, 0); }
        { const ushort* p = pool + buf + 8192 + (wm + 64 + l16) * 32 + chq;
          RD4(ah, p); }                               // A-hi (t,ks1)
        MFMA_G(al, bn, 0);
        if (t <= 14) {
            const ushort* p = pool + bufn + (wm + l16) * 32 + chq;
            RD4(al, p);                               // A-lo (t+1,ks0)
            const ushort* q = pool + bufn + 16384 + (wn + l16) * 32 + chq;
            RD4(bc, q);                               // B    (t+1,ks0)
        }
        MFMA_G(ah, bn, 4);
        if (t <= 13)      { asm volatile("s_waitcnt vmcnt(4)" ::: "memory"); }
        else if (t == 14) { asm volatile("s_waitcnt vmcnt(0)" ::: "memory"); }
        QKV_BARRIER();
    }

    const int nbase  = n0 + wn;
    const int tensor = nbase >> 10;        // wave-uniform (block-uniform)
    const int hh     = (nbase & 1023) >> 6;
    if (tensor < 2) {
        // ---- q/k epilogue with fused RoPE ----
        ushort* Dt = C + (size_t)tensor * ((size_t)MROWS * DMODEL);
        #pragma unroll
        for (int i = 0; i < 8; i++)
            #pragma unroll
            for (int r = 0; r < 4; r++) {
                const int m  = m0 + wm + i * 16 + quad * 4 + r;
                const int bb = m >> 11;
                const int ss = m & (SEQ - 1);
                const float2* trow = tab + ss * 32;
                #pragma unroll
                for (int j = 0; j < 4; j++) {
                    const int f = j * 16 + l16;          // dh 0..63
                    const float2 cs = trow[f >> 1];
                    const float val = acc[i][j][r];
                    const float prt = __shfl_xor(val, 1, 64);
                    const float out = (f & 1) ? (prt * cs.y + val * cs.x)
                                              : (val * cs.x - prt * cs.y);
                    Dt[(((size_t)(bb * NHEAD + hh)) * SEQ + ss) * DHEAD + f] =
                        bf16u(out);
                }
            }
    } else {
        // ---- V^T epilogue: wave-private swizzled LDS transpose ----
        // pool free: each wave's MFMAs consumed its ds_reads pre-barrier
        ushort* Tw = pool + w * 8192;   // 16 KB per wave
        #pragma unroll
        for (int i = 0; i < 8; i++)
            #pragma unroll
            for (int j = 0; j < 4; j++) {
                const int f  = j * 16 + l16;
                const int sx = (f & 7) << 3;
                #pragma unroll
                for (int r = 0; r < 4; r += 2) {
                    const int ml = i * 16 + quad * 4 + r;
                    ushort2 pk;
                    pk.x = bf16u(acc[i][j][r]);
                    pk.y = bf16u(acc[i][j][r + 1]);
                    *reinterpret_cast<ushort2*>(&Tw[f * 128 + (ml ^ sx)]) = pk;
                }
            }
        asm volatile("s_waitcnt lgkmcnt(0)" ::: "memory");
        ushort* Dv = C + 2 * ((size_t)MROWS * DMODEL);
        const int c  = lane & 15;        // m-chunk (8 elems)
        const int fb = lane >> 4;        // f sub-row 0..3
        #pragma unroll
        for (int rr = 0; rr < 16; rr++) {
            const int fl = rr * 4 + fb;
            const uint4 v = *reinterpret_cast<const uint4*>(
                &Tw[fl * 128 + ((c << 3) ^ ((fl & 7) << 3))]);
            *reinterpret_cast<uint4*>(
                &Dv[(size_t)(hh * 64 + fl) * MROWS + m0 + wm + (c << 3)]) = v;
        }
    }
}

// ---------------------------------------------------------------------------
// Output GEMM v2: 128x128 tile, BK=64, 8 waves, register-software-pipelined
// (round 6, unchanged).
// ---------------------------------------------------------------------------
#define RD2(dst, p_)                                                          \
    _Pragma("unroll")                                                         \
    for (int rr_ = 0; rr_ < 2; rr_++)                                         \
        dst[rr_] = *reinterpret_cast<const bf16x8*>((p_) + rr_ * 512);

#define OUT_MFMA_G(AFR, BFR, IOFF)                                            \
    __builtin_amdgcn_s_setprio(1);                                            \
    _Pragma("unroll")                                                         \
    for (int im_ = 0; im_ < 2; im_++)                                         \
        _Pragma("unroll")                                                     \
        for (int jn_ = 0; jn_ < 2; jn_++)                                     \
            acc[(IOFF) + im_][jn_] = __builtin_amdgcn_mfma_f32_16x16x32_bf16( \
                AFR[im_], BFR[jn_], acc[(IOFF) + im_][jn_], 0, 0, 0);         \
    __builtin_amdgcn_s_setprio(0);

__global__ __launch_bounds__(512, 2)
void gemm_out128(const ushort* __restrict__ A, const ushort* __restrict__ B,
                 float* __restrict__ C) {
    __shared__ __align__(16) ushort pool[32768];   // 64 KiB

    // XCD remap: grid (8,32) = 256 blocks; XCD k owns column-block k
    const int orig = blockIdx.y * gridDim.x + blockIdx.x;   // 0..255
    const int n0   = (orig & 7) * 128;
    const int m0   = (orig >> 3) * 128;

    const int tid  = threadIdx.x;
    const int lane = tid & 63;
    const int w    = tid >> 6;
    const int l16  = lane & 15;
    const int quad = lane >> 4;
    const int wm   = (w >> 2) * 64;     // 2 wave-rows (0,64)
    const int wn   = (w & 3) * 32;      // 4 wave-cols (0,32,64,96)
    const int chq  = (quad ^ ((l16 & 3) ^ ((l16 & 4) >> 1))) << 3;
    const int srow = tid >> 2;          // 0..127
    const int ssc  = (tid & 3) ^ ((srow & 3) ^ ((srow & 4) >> 1));

    const int am  = m0 + srow;
    const int abb = am >> 11;
    const int ass = am & (SEQ - 1);
    const ushort* gA = A + ((size_t)(abb * NHEAD)) * SEQ * DHEAD
                         + (size_t)ass * DHEAD + ssc * 8;
    const ushort* gB = B + (size_t)(n0 + srow) * DMODEL + ssc * 8;

    auto stageA = [&](int tt, int ks) {
        load16_lds(gA + tt * (SEQ * DHEAD) + ks * 32,
                   &pool[((tt & 1) << 14) + (ks << 12) + tid * 8]);
    };
    auto stageB = [&](int tt, int ks) {
        load16_lds(gB + tt * 64 + ks * 32,
                   &pool[((tt & 1) << 14) + 8192 + (ks << 12) + tid * 8]);
    };

    // prologue: A00 B00 A01 B01 A10 B10  [6 loads]
    stageA(0, 0); stageB(0, 0);
    stageA(0, 1); stageB(0, 1);
    stageA(1, 0); stageB(1, 0);

    f32x4 acc[4][2];
    #pragma unroll
    for (int i = 0; i < 4; i++)
        #pragma unroll
        for (int j = 0; j < 2; j++) acc[i][j] = (f32x4){0.f, 0.f, 0.f, 0.f};

    asm volatile("s_waitcnt vmcnt(2)" ::: "memory");  // AB(0,0..1) landed
    __builtin_amdgcn_s_barrier();

    bf16x8 al[2], ah[2], bc[2], bn[2];

    // pre-loop: operands of phase (0, ks0)
    { const ushort* p = pool + (wm + l16) * 32 + chq;          RD2(al, p); }
    { const ushort* q = pool + 8192 + (wn + l16) * 32 + chq;   RD2(bc, q); }

    #pragma unroll 1
    for (int t = 0; t < 16; t++) {
        const int buf  = (t & 1) << 14;
        const int bufn = buf ^ 16384;
        // ---------- P0: MFMA (t,ks0); prefetch-read (t,ks1)
        if (t <= 14) { stageA(t + 1, 1); stageB(t + 1, 1); }
        { const ushort* p = pool + buf + (wm + 32 + l16) * 32 + chq;
          RD2(ah, p); }                               // A-hi (t,ks0)
        OUT_MFMA_G(al, bc, 0);                        // acc[0..1]
        { const ushort* p = pool + buf + 4096 + (wm + l16) * 32 + chq;
          RD2(al, p);                                 // A-lo (t,ks1)
          const ushort* q = pool + buf + 8192 + 4096 + (wn + l16) * 32 + chq;
          RD2(bn, q); }                               // B    (t,ks1)
        OUT_MFMA_G(ah, bc, 2);                        // acc[2..3]
        if (t <= 14) { asm volatile("s_waitcnt vmcnt(2)" ::: "memory"); }
        QKV_BARRIER();
        // ---------- P1: MFMA (t,ks1); prefetch-read (t+1,ks0)
        if (t <= 13) { stageA(t + 2, 0); stageB(t + 2, 0); }
        { const ushort* p = pool + buf + 4096 + (wm + 32 + l16) * 32 + chq;
          RD2(ah, p); }                               // A-hi (t,ks1)
        OUT_MFMA_G(al, bn, 0);
        if (t <= 14) {
            const ushort* p = pool + bufn + (wm + l16) * 32 + chq;
            RD2(al, p);                               // A-lo (t+1,ks0)
            const ushort* q = pool + bufn + 8192 + (wn + l16) * 32 + chq;
            RD2(bc, q);                               // B    (t+1,ks0)
        }
        OUT_MFMA_G(ah, bn, 2);
        if (t <= 13)      { asm volatile("s_waitcnt vmcnt(2)" ::: "memory"); }
        else if (t == 14) { asm volatile("s_waitcnt vmcnt(0)" ::: "memory"); }
        QKV_BARRIER();
    }

    #pragma unroll
    for (int i = 0; i < 4; i++)
        #pragma unroll
        for (int r = 0; r < 4; r++) {
            const int m = m0 + wm + i * 16 + quad * 4 + r;
            #pragma unroll
            for (int j = 0; j < 2; j++)
                C[(size_t)m * DMODEL + n0 + wn + j * 16 + l16] = acc[i][j][r];
        }
}

// ---------------------------------------------------------------------------
// MFMA flash attention v6 final (best measured: 43.3-43.4 us): single-barrier
// async-DMA double-buffer + max-free exp2-domain softmax + 4-way l4 row-sum.
// setprio REMOVED (r10 A/B: 43.4 -> 46.3 regression — barrier-locked waves
// all raise priority together, hint cancels, overhead remains).
// ---------------------------------------------------------------------------
__global__ __launch_bounds__(256)
void attn_mfma6(const ushort* __restrict__ qb, const ushort* __restrict__ kb,
                const ushort* __restrict__ vtg, ushort* __restrict__ ob) {
    __shared__ __align__(16) ushort Ks[2][4096];
    __shared__ __align__(16) ushort Vs[2][4096];
    __shared__ ushort Pb[4][16][72];

    const int bh   = blockIdx.x;
    const int b    = bh >> 4;
    const int h    = bh & 15;
    const int qt   = (gridDim.y - 1) - blockIdx.y;
    const int tid  = threadIdx.x;
    const int w    = tid >> 6;
    const int lane = tid & 63;
    const int l16  = lane & 15;
    const int quad = lane >> 4;
    const size_t base = (size_t)bh * SEQ * DHEAD;

    const int qlo = qt * 64 + w * 16;

    const float SC = 0.125f * 1.44269504088896f;
    bf16x8 qa[2];
    {
        const size_t qo = base + (size_t)(qlo + l16) * DHEAD + quad * 8;
        qa[0] = *reinterpret_cast<const bf16x8*>(qb + qo);
        qa[1] = *reinterpret_cast<const bf16x8*>(qb + qo + 32);
        #pragma unroll
        for (int j = 0; j < 8; j++) {
            qa[0][j] = (__bf16)(SC * (float)qa[0][j]);
            qa[1][j] = (__bf16)(SC * (float)qa[1][j]);
        }
    }

    f32x4 oacc[4];
    #pragma unroll
    for (int s = 0; s < 4; s++) oacc[s] = (f32x4){0.f, 0.f, 0.f, 0.f};
    f32x4 l4 = (f32x4){0.f, 0.f, 0.f, 0.f};

    const int c0 = tid,        r0 = c0 >> 3, g0 = (c0 & 7) ^ (r0 & 7);
    const int c1 = 256 + tid,  r1 = c1 >> 3, g1 = (c1 & 7) ^ (r1 & 7);
    const ushort* kg0 = kb + base + (size_t)r0 * DHEAD + g0 * 8;
    const ushort* kg1 = kb + base + (size_t)r1 * DHEAD + g1 * 8;
    const ushort* vg0 = vtg + (size_t)(h * DHEAD + r0) * MROWS + b * SEQ + g0 * 8;
    const ushort* vg1 = vtg + (size_t)(h * DHEAD + r1) * MROWS + b * SEQ + g1 * 8;

    int koff[2][4];
    #pragma unroll
    for (int half = 0; half < 2; half++)
        #pragma unroll
        for (int sub = 0; sub < 4; sub++)
            koff[half][sub] = (sub * 16 + l16) * 64 +
                              (((half * 4 + quad) ^ (l16 & 7)) * 8);

    load16_lds(kg0, &Ks[0][c0 * 8]);
    load16_lds(kg1, &Ks[0][c1 * 8]);
    load16_lds(vg0, &Vs[0][c0 * 8]);
    load16_lds(vg1, &Vs[0][c1 * 8]);

    const int T = qt + 1;
    for (int t = 0; t < T; t++) {
        const int bf = t & 1;
        __syncthreads();
        if (t + 1 < T) {
            const size_t ko = (size_t)(t + 1) * 64 * DHEAD;
            const int    vo = (t + 1) * 64;
            load16_lds(kg0 + ko, &Ks[bf ^ 1][c0 * 8]);
            load16_lds(kg1 + ko, &Ks[bf ^ 1][c1 * 8]);
            load16_lds(vg0 + vo, &Vs[bf ^ 1][c0 * 8]);
            load16_lds(vg1 + vo, &Vs[bf ^ 1][c1 * 8]);
        }

        const bool diag = (t == qt);
        const int nsub = diag ? (w + 1) : 4;
        const int nhv  = diag ? ((w >> 1) + 1) : 2;

        f32x4 sacc[4];
        #pragma unroll
        for (int s = 0; s < 4; s++) sacc[s] = (f32x4){0.f, 0.f, 0.f, 0.f};
        #pragma unroll
        for (int half = 0; half < 2; half++)
            #pragma unroll
            for (int sub = 0; sub < 4; sub++)
                if (sub < nsub) {
                    const bf16x8 kf = *reinterpret_cast<const bf16x8*>(
                        &Ks[bf][koff[half][sub]]);
                    sacc[sub] = __builtin_amdgcn_mfma_f32_16x16x32_bf16(
                        kf, qa[half], sacc[sub], 0, 0, 0);
                }

        float ev[4][4];
        if (diag) {
            const int thr = qlo + l16 - t * 64;
            #pragma unroll
            for (int sub = 0; sub < 4; sub++)
                #pragma unroll
                for (int r = 0; r < 4; r++) {
                    const float e = (sub * 16 + quad * 4 + r <= thr)
                                        ? exp2f(sacc[sub][r]) : 0.f;
                    ev[sub][r] = e;
                    l4[sub] += e;
                }
        } else {
            #pragma unroll
            for (int sub = 0; sub < 4; sub++)
                #pragma unroll
                for (int r = 0; r < 4; r++) {
                    const float e = exp2f(sacc[sub][r]);
                    ev[sub][r] = e;
                    l4[sub] += e;
                }
        }

        #pragma unroll
        for (int sub = 0; sub < 4; sub++) {
            ushort4 pk;
            pk.x = bf16u(ev[sub][0]); pk.y = bf16u(ev[sub][1]);
            pk.z = bf16u(ev[sub][2]); pk.w = bf16u(ev[sub][3]);
            *reinterpret_cast<ushort4*>(&Pb[w][l16][sub * 16 + quad * 4]) = pk;
        }
        bf16x8 pa[2];
        pa[0] = *reinterpret_cast<const bf16x8*>(&Pb[w][l16][quad * 8]);
        pa[1] = *reinterpret_cast<const bf16x8*>(&Pb[w][l16][32 + quad * 8]);

        #pragma unroll
        for (int hk = 0; hk < 2; hk++) {
            if (hk >= nhv) break;
            #pragma unroll
            for (int sf = 0; sf < 4; sf++) {
                const bf16x8 vf = *reinterpret_cast<const bf16x8*>(
                    &Vs[bf][koff[hk][sf]]);
                oacc[sf] = __builtin_amdgcn_mfma_f32_16x16x32_bf16(
                    pa[hk], vf, oacc[sf], 0, 0, 0);
            }
        }
    }

    float l_ = (l4[0] + l4[1]) + (l4[2] + l4[3]);
    l_ += __shfl_xor(l_, 16, 64);
    l_ += __shfl_xor(l_, 32, 64);
    float inv[4];
    #pragma unroll
    for (int r = 0; r < 4; r++) inv[r] = 1.f / __shfl(l_, quad * 4 + r, 64);
    #pragma unroll
    for (int sub = 0; sub < 4; sub++)
        #pragma unroll
        for (int r = 0; r < 4; r++) {
            const int q = qlo + quad * 4 + r;
            ob[base + (size_t)q * DHEAD + sub * 16 + l16] =
                bf16u(oacc[sub][r] * inv[r]);
        }
}

// ---------------------------------------------------------------------------
extern "C" void kernel_launch(void* const* d_in, const int* in_sizes, int n_in,
                              void* d_out, int out_size, void* d_ws, size_t ws_size,
                              hipStream_t stream) {
    const float* x  = (const float*)d_in[0];
    const float* Wq = (const float*)d_in[1];
    const float* Wk = (const float*)d_in[2];
    const float* Wv = (const float*)d_in[3];
    const float* Wo = (const float*)d_in[4];
    const int* pos = (const int*)d_in[5];

    const size_t TEN = (size_t)MROWS * DMODEL;   // 4M elements
    const size_t WEL = (size_t)DMODEL * DMODEL;  // 1M elements
    ushort* xb   = (ushort*)d_ws;      // 8 MB
    ushort* Wqkv = xb + TEN;           // 8 MB (Wq,Wk,Wv,Wo contiguous)
    ushort* Wob  = Wqkv + 3 * WEL;
    ushort* qb   = Wob + WEL;          // 8 MB each; kb, vtb contiguous
    ushort* kb   = qb + TEN;
    ushort* vtb  = kb + TEN;           // V^T [1024][4096]
    ushort* ob   = vtb + TEN;
    float2* tab  = (float2*)(ob + TEN);  // 512 KB rope table

    dim3 blk(256);
    rope_tab<<<(SEQ * 32) / 256, blk, 0, stream>>>(pos, tab);
    cast_all<<<(TEN + 4 * WEL) / (8 * 256), blk, 0, stream>>>(
        x, Wq, Wk, Wv, Wo, xb, Wqkv);

    dim3 gqkv(3 * DMODEL / 256, MROWS / 256);   // (12, 16) = 192 blocks
    gemm_qkv<<<gqkv, dim3(512), 0, stream>>>(xb, Wqkv, qb, tab);

    dim3 gattn(BATCH * NHEAD, SEQ / 64);        // (32, 32)
    attn_mfma6<<<gattn, blk, 0, stream>>>(qb, kb, vtb, ob);

    dim3 gout(DMODEL / 128, MROWS / 128);       // (8, 32) = 256 blocks
    gemm_out128<<<gout, dim3(512), 0, stream>>>(ob, Wob, (float*)d_out);
}

// Round 12
// 177.754 us; speedup vs baseline: 1.0114x; 1.0114x over previous
//
#include <hip/hip_runtime.h>
#include <hip/hip_bf16.h>
#include <math.h>

#define DMODEL 1024
#define NHEAD  16
#define DHEAD  64
#define BATCH  2
#define SEQ    2048
#define MROWS  (BATCH * SEQ)   // 4096

typedef __attribute__((ext_vector_type(8))) __bf16 bf16x8;
typedef __attribute__((ext_vector_type(4))) float  f32x4;

// async global->LDS, 16 B per lane. LDS dest must be wave-uniform base + lane*16.
__device__ __forceinline__ void load16_lds(const ushort* g, ushort* l) {
    __builtin_amdgcn_global_load_lds(
        (const __attribute__((address_space(1))) unsigned int*)g,
        (__attribute__((address_space(3))) unsigned int*)l, 16, 0, 0);
}

__device__ __forceinline__ ushort bf16u(float v) {
    __hip_bfloat16 h = __float2bfloat16(v);
    return *reinterpret_cast<ushort*>(&h);
}

// ---------------------------------------------------------------------------
// fused fp32 -> bf16 cast of x (4M elems) + Wq/Wk/Wv/Wo (1M each, contiguous
// destination Wqkv..Wob). One dispatch, source picked by linear range.
// Kept SEPARATE from rope_tab: merging forces the memory-bound cast path to
// carry sincosf's register footprint (r9 vs r6: +3.4 us).
// ---------------------------------------------------------------------------
__global__ __launch_bounds__(256)
void cast_all(const float* __restrict__ x,  const float* __restrict__ w0,
              const float* __restrict__ w1, const float* __restrict__ w2,
              const float* __restrict__ w3, ushort* __restrict__ xb,
              ushort* __restrict__ wb) {
    const int idx = (blockIdx.x * 256 + threadIdx.x) * 8;   // 0..8M-8
    const int TEN_ = MROWS * DMODEL;                        // 4M
    const float* src;
    ushort* dst;
    if (idx < TEN_) {
        src = x + idx;  dst = xb + idx;
    } else {
        const int r   = idx - TEN_;                         // 0..4M-8
        const int sel = r >> 20;                            // 0..3 (WEL = 1M)
        const int off = r & (DMODEL * DMODEL - 1);
        src = (sel == 0 ? w0 : sel == 1 ? w1 : sel == 2 ? w2 : w3) + off;
        dst = wb + r;
    }
    const f32x4 a = *reinterpret_cast<const f32x4*>(src);
    const f32x4 b = *reinterpret_cast<const f32x4*>(src + 4);
    bf16x8 o;
    #pragma unroll
    for (int j = 0; j < 4; j++) { o[j] = (__bf16)a[j]; o[4 + j] = (__bf16)b[j]; }
    *reinterpret_cast<bf16x8*>(dst) = o;
}

// ---------------------------------------------------------------------------
// RoPE cos/sin table: tab[s*32+i] = (cos, sin) of pos[s] * 10000^(-2i/64).
// ---------------------------------------------------------------------------
__global__ __launch_bounds__(256)
void rope_tab(const int* __restrict__ pos, float2* __restrict__ tab) {
    const int idx = blockIdx.x * 256 + threadIdx.x;   // 0..65535
    const int s = idx >> 5;
    const int i = idx & 31;
    const float p = (float)pos[s];
    const float inv = exp2f(-(float)i * 0.41524101186092f);  // 2*log2(1e4)/64
    float sn, cs;
    sincosf(p * inv, &sn, &cs);
    tab[idx] = make_float2(cs, sn);
}

#define QKV_BARRIER() do { asm volatile("" ::: "memory"); \
                           __builtin_amdgcn_s_barrier(); } while (0)

#define RD2(dst, p_)                                                          \
    _Pragma("unroll")                                                         \
    for (int rr_ = 0; rr_ < 2; rr_++)                                         \
        dst[rr_] = *reinterpret_cast<const bf16x8*>((p_) + rr_ * 512);

#define MFMA_G2(AFR, BFR, IOFF)                                               \
    __builtin_amdgcn_s_setprio(1);                                            \
    _Pragma("unroll")                                                         \
    for (int im_ = 0; im_ < 2; im_++)                                         \
        _Pragma("unroll")                                                     \
        for (int jn_ = 0; jn_ < 2; jn_++)                                     \
            acc[(IOFF) + im_][jn_] = __builtin_amdgcn_mfma_f32_16x16x32_bf16( \
                AFR[im_], BFR[jn_], acc[(IOFF) + im_][jn_], 0, 0, 0);         \
    __builtin_amdgcn_s_setprio(0);

// ---------------------------------------------------------------------------
// Fused QKV GEMM v2: 128x128 tile, BK=64, 8 waves, register-software-
// pipelined (the gemm_out128 skeleton, verified r6-r11). Rationale: the 256²
// version held 128 KiB LDS -> 1 block/CU and 192 blocks on 256 CUs (25% CUs
// idle, MfmaUtil 21%, 66% issue slots idle). 64 KiB LDS -> 2 blocks/CU and
// 768 blocks: co-resident de-phased blocks fill each other's stalls.
// Epilogues (fused RoPE q/k, V^T transpose) re-derived for 128-col blocks.
// ---------------------------------------------------------------------------
__global__ __launch_bounds__(512, 2)
void gemm_qkv(const ushort* __restrict__ A, const ushort* __restrict__ B,
              ushort* __restrict__ C, const float2* __restrict__ tab) {
    __shared__ __align__(16) ushort pool[32768];   // 64 KiB

    // bijective XCD remap: 768 blocks = 8 XCDs x 96; each XCD owns a 512-row
    // A-stripe (4 by) x 24 bx (A-panel 1 MB L2-resident per XCD).
    const int orig = blockIdx.y * gridDim.x + blockIdx.x;   // 0..767
    const int xcd  = orig & 7;
    const int ixd  = orig >> 3;                             // 0..95
    const int by   = xcd * 4 + (ixd / 24);                  // 0..31
    const int bx   = ixd % 24;                              // 0..23
    const int m0   = by * 128;
    const int n0   = bx * 128;

    const int tid  = threadIdx.x;
    const int lane = tid & 63;
    const int w    = tid >> 6;
    const int l16  = lane & 15;
    const int quad = lane >> 4;
    const int wm   = (w >> 2) * 64;     // 2 wave-rows (0,64)
    const int wn   = (w & 3) * 32;      // 4 wave-cols (0,32,64,96)
    const int chq  = (quad ^ ((l16 & 3) ^ ((l16 & 4) >> 1))) << 3;
    const int srow = tid >> 2;          // 0..127
    const int ssc  = (tid & 3) ^ ((srow & 3) ^ ((srow & 4) >> 1));

    // hoisted staging bases (pre-swizzled global source); both dense rows
    const ushort* gA = A + (size_t)(m0 + srow) * DMODEL + ssc * 8;
    const ushort* gB = B + (size_t)(n0 + srow) * DMODEL + ssc * 8;

    auto stageA = [&](int tt, int ks) {
        load16_lds(gA + tt * 64 + ks * 32,
                   &pool[((tt & 1) << 14) + (ks << 12) + tid * 8]);
    };
    auto stageB = [&](int tt, int ks) {
        load16_lds(gB + tt * 64 + ks * 32,
                   &pool[((tt & 1) << 14) + 8192 + (ks << 12) + tid * 8]);
    };

    // prologue: A00 B00 A01 B01 A10 B10  [6 loads]
    stageA(0, 0); stageB(0, 0);
    stageA(0, 1); stageB(0, 1);
    stageA(1, 0); stageB(1, 0);

    f32x4 acc[4][2];
    #pragma unroll
    for (int i = 0; i < 4; i++)
        #pragma unroll
        for (int j = 0; j < 2; j++) acc[i][j] = (f32x4){0.f, 0.f, 0.f, 0.f};

    asm volatile("s_waitcnt vmcnt(2)" ::: "memory");  // AB(0,0..1) landed
    __builtin_amdgcn_s_barrier();

    bf16x8 al[2], ah[2], bc[2], bn[2];

    // pre-loop: operands of phase (0, ks0)
    { const ushort* p = pool + (wm + l16) * 32 + chq;          RD2(al, p); }
    { const ushort* q = pool + 8192 + (wn + l16) * 32 + chq;   RD2(bc, q); }

    #pragma unroll 1
    for (int t = 0; t < 16; t++) {
        const int buf  = (t & 1) << 14;
        const int bufn = buf ^ 16384;
        // ---------- P0: MFMA (t,ks0); prefetch-read (t,ks1)
        if (t <= 14) { stageA(t + 1, 1); stageB(t + 1, 1); }
        { const ushort* p = pool + buf + (wm + 32 + l16) * 32 + chq;
          RD2(ah, p); }                               // A-hi (t,ks0)
        MFMA_G2(al, bc, 0);                           // acc[0..1]
        { const ushort* p = pool + buf + 4096 + (wm + l16) * 32 + chq;
          RD2(al, p);                                 // A-lo (t,ks1)
          const ushort* q = pool + buf + 8192 + 4096 + (wn + l16) * 32 + chq;
          RD2(bn, q); }                               // B    (t,ks1)
        MFMA_G2(ah, bc, 2);                           // acc[2..3]
        if (t <= 14) { asm volatile("s_waitcnt vmcnt(2)" ::: "memory"); }
        QKV_BARRIER();
        // ---------- P1: MFMA (t,ks1); prefetch-read (t+1,ks0)
        if (t <= 13) { stageA(t + 2, 0); stageB(t + 2, 0); }
        { const ushort* p = pool + buf + 4096 + (wm + 32 + l16) * 32 + chq;
          RD2(ah, p); }                               // A-hi (t,ks1)
        MFMA_G2(al, bn, 0);
        if (t <= 14) {
            const ushort* p = pool + bufn + (wm + l16) * 32 + chq;
            RD2(al, p);                               // A-lo (t+1,ks0)
            const ushort* q = pool + bufn + 8192 + (wn + l16) * 32 + chq;
            RD2(bc, q);                               // B    (t+1,ks0)
        }
        MFMA_G2(ah, bn, 2);
        if (t <= 13)      { asm volatile("s_waitcnt vmcnt(2)" ::: "memory"); }
        else if (t == 14) { asm volatile("s_waitcnt vmcnt(0)" ::: "memory"); }
        QKV_BARRIER();
    }
    // loop ends at a barrier; every wave's ds_reads were consumed by its
    // MFMAs before that barrier -> pool is free for the V^T overlay below.

    const int nbase  = n0 + wn;            // 32-aligned; block spans one tensor
    const int tensor = nbase >> 10;
    if (tensor < 2) {
        // ---- q/k epilogue with fused RoPE (head can vary with j) ----
        ushort* Dt = C + (size_t)tensor * ((size_t)MROWS * DMODEL);
        #pragma unroll
        for (int i = 0; i < 4; i++)
            #pragma unroll
            for (int r = 0; r < 4; r++) {
                const int m  = m0 + wm + i * 16 + quad * 4 + r;
                const int bb = m >> 11;
                const int ss = m & (SEQ - 1);
                const float2* trow = tab + ss * 32;
                #pragma unroll
                for (int j = 0; j < 2; j++) {
                    const int ncol = (nbase & 1023) + j * 16;  // 16-aligned
                    const int hh   = ncol >> 6;
                    const int f    = (ncol & 63) + l16;        // dh 0..63
                    const float2 cs = trow[f >> 1];
                    const float val = acc[i][j][r];
                    const float prt = __shfl_xor(val, 1, 64);
                    const float out = (f & 1) ? (prt * cs.y + val * cs.x)
                                              : (val * cs.x - prt * cs.y);
                    Dt[(((size_t)(bb * NHEAD + hh)) * SEQ + ss) * DHEAD + f] =
                        bf16u(out);
                }
            }
    } else {
        // ---- V^T epilogue: wave-private swizzled LDS transpose ----
        // wave owns 64 rows (m) x 32 cols; Tw = 32 x 64 ushorts = 8 KB
        ushort* Tw = pool + w * 4096;
        #pragma unroll
        for (int i = 0; i < 4; i++)
            #pragma unroll
            for (int j = 0; j < 2; j++) {
                const int cl = j * 16 + l16;       // local col 0..31
                const int sx = (cl & 7) << 3;
                #pragma unroll
                for (int r = 0; r < 4; r += 2) {
                    const int ml = i * 16 + quad * 4 + r;   // local row 0..63
                    ushort2 pk;
                    pk.x = bf16u(acc[i][j][r]);
                    pk.y = bf16u(acc[i][j][r + 1]);
                    *reinterpret_cast<ushort2*>(&Tw[cl * 64 + (ml ^ sx)]) = pk;
                }
            }
        asm volatile("s_waitcnt lgkmcnt(0)" ::: "memory");
        ushort* Dv = C + 2 * ((size_t)MROWS * DMODEL);
        const int c  = lane & 7;         // m-chunk (8 elems)
        const int fb = lane >> 3;        // col sub-group 0..7
        #pragma unroll
        for (int rr = 0; rr < 4; rr++) {
            const int cl = rr * 8 + fb;  // local col 0..31
            const uint4 v = *reinterpret_cast<const uint4*>(
                &Tw[cl * 64 + ((c << 3) ^ ((cl & 7) << 3))]);
            *reinterpret_cast<uint4*>(
                &Dv[(size_t)((nbase & 1023) + cl) * MROWS + m0 + wm + (c << 3)])
                = v;
        }
    }
}

// ---------------------------------------------------------------------------
// Output GEMM v2: 128x128 tile, BK=64, 8 waves, register-software-pipelined
// (round 6, unchanged).
// ---------------------------------------------------------------------------
__global__ __launch_bounds__(512, 2)
void gemm_out128(const ushort* __restrict__ A, const ushort* __restrict__ B,
                 float* __restrict__ C) {
    __shared__ __align__(16) ushort pool[32768];   // 64 KiB

    // XCD remap: grid (8,32) = 256 blocks; XCD k owns column-block k
    const int orig = blockIdx.y * gridDim.x + blockIdx.x;   // 0..255
    const int n0   = (orig & 7) * 128;
    const int m0   = (orig >> 3) * 128;

    const int tid  = threadIdx.x;
    const int lane = tid & 63;
    const int w    = tid >> 6;
    const int l16  = lane & 15;
    const int quad = lane >> 4;
    const int wm   = (w >> 2) * 64;     // 2 wave-rows (0,64)
    const int wn   = (w & 3) * 32;      // 4 wave-cols (0,32,64,96)
    const int chq  = (quad ^ ((l16 & 3) ^ ((l16 & 4) >> 1))) << 3;
    const int srow = tid >> 2;          // 0..127
    const int ssc  = (tid & 3) ^ ((srow & 3) ^ ((srow & 4) >> 1));

    const int am  = m0 + srow;
    const int abb = am >> 11;
    const int ass = am & (SEQ - 1);
    const ushort* gA = A + ((size_t)(abb * NHEAD)) * SEQ * DHEAD
                         + (size_t)ass * DHEAD + ssc * 8;
    const ushort* gB = B + (size_t)(n0 + srow) * DMODEL + ssc * 8;

    auto stageA = [&](int tt, int ks) {
        load16_lds(gA + tt * (SEQ * DHEAD) + ks * 32,
                   &pool[((tt & 1) << 14) + (ks << 12) + tid * 8]);
    };
    auto stageB = [&](int tt, int ks) {
        load16_lds(gB + tt * 64 + ks * 32,
                   &pool[((tt & 1) << 14) + 8192 + (ks << 12) + tid * 8]);
    };

    // prologue: A00 B00 A01 B01 A10 B10  [6 loads]
    stageA(0, 0); stageB(0, 0);
    stageA(0, 1); stageB(0, 1);
    stageA(1, 0); stageB(1, 0);

    f32x4 acc[4][2];
    #pragma unroll
    for (int i = 0; i < 4; i++)
        #pragma unroll
        for (int j = 0; j < 2; j++) acc[i][j] = (f32x4){0.f, 0.f, 0.f, 0.f};

    asm volatile("s_waitcnt vmcnt(2)" ::: "memory");  // AB(0,0..1) landed
    __builtin_amdgcn_s_barrier();

    bf16x8 al[2], ah[2], bc[2], bn[2];

    // pre-loop: operands of phase (0, ks0)
    { const ushort* p = pool + (wm + l16) * 32 + chq;          RD2(al, p); }
    { const ushort* q = pool + 8192 + (wn + l16) * 32 + chq;   RD2(bc, q); }

    #pragma unroll 1
    for (int t = 0; t < 16; t++) {
        const int buf  = (t & 1) << 14;
        const int bufn = buf ^ 16384;
        // ---------- P0: MFMA (t,ks0); prefetch-read (t,ks1)
        if (t <= 14) { stageA(t + 1, 1); stageB(t + 1, 1); }
        { const ushort* p = pool + buf + (wm + 32 + l16) * 32 + chq;
          RD2(ah, p); }                               // A-hi (t,ks0)
        MFMA_G2(al, bc, 0);                           // acc[0..1]
        { const ushort* p = pool + buf + 4096 + (wm + l16) * 32 + chq;
          RD2(al, p);                                 // A-lo (t,ks1)
          const ushort* q = pool + buf + 8192 + 4096 + (wn + l16) * 32 + chq;
          RD2(bn, q); }                               // B    (t,ks1)
        MFMA_G2(ah, bc, 2);                           // acc[2..3]
        if (t <= 14) { asm volatile("s_waitcnt vmcnt(2)" ::: "memory"); }
        QKV_BARRIER();
        // ---------- P1: MFMA (t,ks1); prefetch-read (t+1,ks0)
        if (t <= 13) { stageA(t + 2, 0); stageB(t + 2, 0); }
        { const ushort* p = pool + buf + 4096 + (wm + 32 + l16) * 32 + chq;
          RD2(ah, p); }                               // A-hi (t,ks1)
        MFMA_G2(al, bn, 0);
        if (t <= 14) {
            const ushort* p = pool + bufn + (wm + l16) * 32 + chq;
            RD2(al, p);                               // A-lo (t+1,ks0)
            const ushort* q = pool + bufn + 8192 + (wn + l16) * 32 + chq;
            RD2(bc, q);                               // B    (t+1,ks0)
        }
        MFMA_G2(ah, bn, 2);
        if (t <= 13)      { asm volatile("s_waitcnt vmcnt(2)" ::: "memory"); }
        else if (t == 14) { asm volatile("s_waitcnt vmcnt(0)" ::: "memory"); }
        QKV_BARRIER();
    }

    #pragma unroll
    for (int i = 0; i < 4; i++)
        #pragma unroll
        for (int r = 0; r < 4; r++) {
            const int m = m0 + wm + i * 16 + quad * 4 + r;
            #pragma unroll
            for (int j = 0; j < 2; j++)
                C[(size_t)m * DMODEL + n0 + wn + j * 16 + l16] = acc[i][j][r];
        }
}

// ---------------------------------------------------------------------------
// MFMA flash attention v6 final (best measured: 43.2-43.6 us): single-barrier
// async-DMA double-buffer + max-free exp2-domain softmax + 4-way l4 row-sum.
// setprio removed (r10 A/B regression).
// ---------------------------------------------------------------------------
__global__ __launch_bounds__(256)
void attn_mfma6(const ushort* __restrict__ qb, const ushort* __restrict__ kb,
                const ushort* __restrict__ vtg, ushort* __restrict__ ob) {
    __shared__ __align__(16) ushort Ks[2][4096];
    __shared__ __align__(16) ushort Vs[2][4096];
    __shared__ ushort Pb[4][16][72];

    const int bh   = blockIdx.x;
    const int b    = bh >> 4;
    const int h    = bh & 15;
    const int qt   = (gridDim.y - 1) - blockIdx.y;
    const int tid  = threadIdx.x;
    const int w    = tid >> 6;
    const int lane = tid & 63;
    const int l16  = lane & 15;
    const int quad = lane >> 4;
    const size_t base = (size_t)bh * SEQ * DHEAD;

    const int qlo = qt * 64 + w * 16;

    const float SC = 0.125f * 1.44269504088896f;
    bf16x8 qa[2];
    {
        const size_t qo = base + (size_t)(qlo + l16) * DHEAD + quad * 8;
        qa[0] = *reinterpret_cast<const bf16x8*>(qb + qo);
        qa[1] = *reinterpret_cast<const bf16x8*>(qb + qo + 32);
        #pragma unroll
        for (int j = 0; j < 8; j++) {
            qa[0][j] = (__bf16)(SC * (float)qa[0][j]);
            qa[1][j] = (__bf16)(SC * (float)qa[1][j]);
        }
    }

    f32x4 oacc[4];
    #pragma unroll
    for (int s = 0; s < 4; s++) oacc[s] = (f32x4){0.f, 0.f, 0.f, 0.f};
    f32x4 l4 = (f32x4){0.f, 0.f, 0.f, 0.f};

    const int c0 = tid,        r0 = c0 >> 3, g0 = (c0 & 7) ^ (r0 & 7);
    const int c1 = 256 + tid,  r1 = c1 >> 3, g1 = (c1 & 7) ^ (r1 & 7);
    const ushort* kg0 = kb + base + (size_t)r0 * DHEAD + g0 * 8;
    const ushort* kg1 = kb + base + (size_t)r1 * DHEAD + g1 * 8;
    const ushort* vg0 = vtg + (size_t)(h * DHEAD + r0) * MROWS + b * SEQ + g0 * 8;
    const ushort* vg1 = vtg + (size_t)(h * DHEAD + r1) * MROWS + b * SEQ + g1 * 8;

    int koff[2][4];
    #pragma unroll
    for (int half = 0; half < 2; half++)
        #pragma unroll
        for (int sub = 0; sub < 4; sub++)
            koff[half][sub] = (sub * 16 + l16) * 64 +
                              (((half * 4 + quad) ^ (l16 & 7)) * 8);

    load16_lds(kg0, &Ks[0][c0 * 8]);
    load16_lds(kg1, &Ks[0][c1 * 8]);
    load16_lds(vg0, &Vs[0][c0 * 8]);
    load16_lds(vg1, &Vs[0][c1 * 8]);

    const int T = qt + 1;
    for (int t = 0; t < T; t++) {
        const int bf = t & 1;
        __syncthreads();
        if (t + 1 < T) {
            const size_t ko = (size_t)(t + 1) * 64 * DHEAD;
            const int    vo = (t + 1) * 64;
            load16_lds(kg0 + ko, &Ks[bf ^ 1][c0 * 8]);
            load16_lds(kg1 + ko, &Ks[bf ^ 1][c1 * 8]);
            load16_lds(vg0 + vo, &Vs[bf ^ 1][c0 * 8]);
            load16_lds(vg1 + vo, &Vs[bf ^ 1][c1 * 8]);
        }

        const bool diag = (t == qt);
        const int nsub = diag ? (w + 1) : 4;
        const int nhv  = diag ? ((w >> 1) + 1) : 2;

        f32x4 sacc[4];
        #pragma unroll
        for (int s = 0; s < 4; s++) sacc[s] = (f32x4){0.f, 0.f, 0.f, 0.f};
        #pragma unroll
        for (int half = 0; half < 2; half++)
            #pragma unroll
            for (int sub = 0; sub < 4; sub++)
                if (sub < nsub) {
                    const bf16x8 kf = *reinterpret_cast<const bf16x8*>(
                        &Ks[bf][koff[half][sub]]);
                    sacc[sub] = __builtin_amdgcn_mfma_f32_16x16x32_bf16(
                        kf, qa[half], sacc[sub], 0, 0, 0);
                }

        float ev[4][4];
        if (diag) {
            const int thr = qlo + l16 - t * 64;
            #pragma unroll
            for (int sub = 0; sub < 4; sub++)
                #pragma unroll
                for (int r = 0; r < 4; r++) {
                    const float e = (sub * 16 + quad * 4 + r <= thr)
                                        ? exp2f(sacc[sub][r]) : 0.f;
                    ev[sub][r] = e;
                    l4[sub] += e;
                }
        } else {
            #pragma unroll
            for (int sub = 0; sub < 4; sub++)
                #pragma unroll
                for (int r = 0; r < 4; r++) {
                    const float e = exp2f(sacc[sub][r]);
                    ev[sub][r] = e;
                    l4[sub] += e;
                }
        }

        #pragma unroll
        for (int sub = 0; sub < 4; sub++) {
            ushort4 pk;
            pk.x = bf16u(ev[sub][0]); pk.y = bf16u(ev[sub][1]);
            pk.z = bf16u(ev[sub][2]); pk.w = bf16u(ev[sub][3]);
            *reinterpret_cast<ushort4*>(&Pb[w][l16][sub * 16 + quad * 4]) = pk;
        }
        bf16x8 pa[2];
        pa[0] = *reinterpret_cast<const bf16x8*>(&Pb[w][l16][quad * 8]);
        pa[1] = *reinterpret_cast<const bf16x8*>(&Pb[w][l16][32 + quad * 8]);

        #pragma unroll
        for (int hk = 0; hk < 2; hk++) {
            if (hk >= nhv) break;
            #pragma unroll
            for (int sf = 0; sf < 4; sf++) {
                const bf16x8 vf = *reinterpret_cast<const bf16x8*>(
                    &Vs[bf][koff[hk][sf]]);
                oacc[sf] = __builtin_amdgcn_mfma_f32_16x16x32_bf16(
                    pa[hk], vf, oacc[sf], 0, 0, 0);
            }
        }
    }

    float l_ = (l4[0] + l4[1]) + (l4[2] + l4[3]);
    l_ += __shfl_xor(l_, 16, 64);
    l_ += __shfl_xor(l_, 32, 64);
    float inv[4];
    #pragma unroll
    for (int r = 0; r < 4; r++) inv[r] = 1.f / __shfl(l_, quad * 4 + r, 64);
    #pragma unroll
    for (int sub = 0; sub < 4; sub++)
        #pragma unroll
        for (int r = 0; r < 4; r++) {
            const int q = qlo + quad * 4 + r;
            ob[base + (size_t)q * DHEAD + sub * 16 + l16] =
                bf16u(oacc[sub][r] * inv[r]);
        }
}

// ---------------------------------------------------------------------------
extern "C" void kernel_launch(void* const* d_in, const int* in_sizes, int n_in,
                              void* d_out, int out_size, void* d_ws, size_t ws_size,
                              hipStream_t stream) {
    const float* x  = (const float*)d_in[0];
    const float* Wq = (const float*)d_in[1];
    const float* Wk = (const float*)d_in[2];
    const float* Wv = (const float*)d_in[3];
    const float* Wo = (const float*)d_in[4];
    const int* pos = (const int*)d_in[5];

    const size_t TEN = (size_t)MROWS * DMODEL;   // 4M elements
    const size_t WEL = (size_t)DMODEL * DMODEL;  // 1M elements
    ushort* xb   = (ushort*)d_ws;      // 8 MB
    ushort* Wqkv = xb + TEN;           // 8 MB (Wq,Wk,Wv,Wo contiguous)
    ushort* Wob  = Wqkv + 3 * WEL;
    ushort* qb   = Wob + WEL;          // 8 MB each; kb, vtb contiguous
    ushort* kb   = qb + TEN;
    ushort* vtb  = kb + TEN;           // V^T [1024][4096]
    ushort* ob   = vtb + TEN;
    float2* tab  = (float2*)(ob + TEN);  // 512 KB rope table

    dim3 blk(256);
    rope_tab<<<(SEQ * 32) / 256, blk, 0, stream>>>(pos, tab);
    cast_all<<<(TEN + 4 * WEL) / (8 * 256), blk, 0, stream>>>(
        x, Wq, Wk, Wv, Wo, xb, Wqkv);

    dim3 gqkv(3 * DMODEL / 128, MROWS / 128);   // (24, 32) = 768 blocks
    gemm_qkv<<<gqkv, dim3(512), 0, stream>>>(xb, Wqkv, qb, tab);

    dim3 gattn(BATCH * NHEAD, SEQ / 64);        // (32, 32)
    attn_mfma6<<<gattn, blk, 0, stream>>>(qb, kb, vtb, ob);

    dim3 gout(DMODEL / 128, MROWS / 128);       // (8, 32) = 256 blocks
    gemm_out128<<<gout, dim3(512), 0, stream>>>(ob, Wob, (float*)d_out);
}